// Round 20
// baseline (224.607 us; speedup 1.0000x reference)
//
#include <hip/hip_runtime.h>
#include <math.h>

#define B_ 32
#define L_ 512
#define H_ 336
#define C_ 321
#define K_ 8
#define S_ 8
#define FREQ_ 169   // H/2+1
#define G_ 17       // 2K+1
#define LHB_ 848    // L+H (bf16 row length)
#define F_FEAT 520  // L+K
#define EPS_ 1e-5f
#define BCN_ (B_ * C_)    // 10272
#define DZB_ 7            // bc per k_dftz2 block (63 of 64 M-rows)

#ifndef M_PIf
#define M_PIf 3.14159265358979323846f
#endif

typedef __attribute__((ext_vector_type(8))) short short8v;
typedef __attribute__((ext_vector_type(4))) float f32x4;

__device__ __forceinline__ unsigned short f2bf(float x) {
    unsigned u = __builtin_bit_cast(unsigned, x);
    u += 0x7FFFu + ((u >> 16) & 1u);
    return (unsigned short)(u >> 16);
}
__device__ __forceinline__ float bf2f(unsigned short h) {
    return __builtin_bit_cast(float, (unsigned)h << 16);
}

// ================= merged prep A: {Tdft, ctb/stb, Wbsw, stf4/stg3} ===========
// Fragment layout (16x16x32 bf16): b-frag lane l holds B[kc*32 + (l>>4)*8 + i][nt*16 + (l&15)].
__global__ __launch_bounds__(256) void k_prepA(const float* __restrict__ Wb,
                                               const float* __restrict__ st_re,
                                               const float* __restrict__ st_im,
                                               unsigned short* __restrict__ Tdft,
                                               float* __restrict__ ctb,
                                               float* __restrict__ stb,
                                               unsigned short* __restrict__ Wbsw,
                                               float4* __restrict__ stf4,
                                               float2* __restrict__ stg3) {
    int bid = blockIdx.x, tid = threadIdx.x;
    if (bid < 61) {
        // DFT table: 242 logical 64-thr blocks
        int orig = bid * 4 + (tid >> 6);
        if (orig < 11 * 22) {
            int lane = tid & 63;
            int kc = orig / 22, nt = orig % 22;
            int n = nt * 16 + (lane & 15);
            int kb = kc * 32 + (lane >> 4) * 8;
            int f = n >> 1;
            unsigned short* dst = Tdft + (size_t)orig * 512 + lane * 8;
            for (int i = 0; i < 8; ++i) {
                int k = kb + i;
                float val = 0.f;
                if (k < H_ && n < 2 * FREQ_) {
                    int m = (k * f) % H_;
                    float s, c;
                    sincosf((float)m * (2.0f * M_PIf / (float)H_), &s, &c);
                    val = (n & 1) ? -s : c;
                }
                dst[i] = f2bf(val);
            }
        }
    } else if (bid < 283) {
        // weighted twiddle tables
        int idx = (bid - 61) * 256 + tid;
        if (idx < FREQ_ * H_) {
            int g = idx / H_, h = idx % H_;
            int m = (g * h) % H_;
            float s, c;
            sincosf((float)m * (2.0f * M_PIf / (float)H_), &s, &c);
            float wgt = ((g == 0 || g == FREQ_ - 1) ? 1.0f : 2.0f) * (1.0f / (float)H_);
            ctb[idx] = wgt * c;
            stb[idx] = -wgt * s;
        }
    } else if (bid < 367) {
        // Wb swizzle: 336 logical 64-thr blocks
        int orig = (bid - 283) * 4 + (tid >> 6);
        if (orig < 16 * 21) {
            int lane = tid & 63;
            int kc = orig / 21, nt = orig % 21;
            int n = nt * 16 + (lane & 15);
            int kb = kc * 32 + (lane >> 4) * 8;
            unsigned short* dst = Wbsw + (size_t)orig * 512 + lane * 8;
            for (int i = 0; i < 8; ++i) {
                int k = kb + i;
                dst[i] = f2bf(Wb[(size_t)n * L_ + k]);
            }
        }
    } else {
        // states repack
        int idx = (bid - 367) * 256 + tid;
        if (idx < 64 * FREQ_) {
            int row = idx / FREQ_, f = idx % FREQ_;
            int k = row >> 3, s = row & 7;
            size_t b1 = (size_t)s * (G_ * FREQ_) + (size_t)k * FREQ_ + f;
            size_t b2 = (size_t)s * (G_ * FREQ_) + (size_t)(8 + k) * FREQ_ + f;
            stf4[idx] = make_float4(st_re[b1], st_im[b1], st_re[b2], st_im[b2]);
        }
        if (idx < 8 * FREQ_) {
            int s = idx / FREQ_, f = idx % FREQ_;
            size_t b3 = (size_t)s * (G_ * FREQ_) + (size_t)16 * FREQ_ + f;
            stg3[idx] = make_float2(st_re[b3], st_im[b3]);
        }
    }
}

// ================= merged prep B: {WTsw, bvec} (needs ctb/stb) ===============
__global__ __launch_bounds__(256) void k_prepB(const float* __restrict__ Wm_re,
                                               const float* __restrict__ Wm_im,
                                               const float* __restrict__ bm_re,
                                               const float* __restrict__ bm_im,
                                               const float* __restrict__ ctb,
                                               const float* __restrict__ stb,
                                               unsigned short* __restrict__ T,
                                               float* __restrict__ bvec) {
    int bid = blockIdx.x, tid = threadIdx.x;
    if (bid < 672) {
        int t = bid * 256 + tid;
        if (t >= 512 * H_) return;
        int k = t / H_, h = t - k * H_;
        float s1 = 0.f, s2 = 0.f;
        if (k < 3 * FREQ_) {
            #pragma unroll 4
            for (int g = 0; g < FREQ_; ++g) {
                float ct = ctb[g * H_ + h];
                float st = stb[g * H_ + h];
                float wr = Wm_re[(size_t)g * (3 * FREQ_) + k];
                float wi = Wm_im[(size_t)g * (3 * FREQ_) + k];
                s1 += wr * ct + wi * st;
                s2 += wr * st - wi * ct;
            }
        }
        int nt = h >> 4, nr = h & 15;
        {
            int kc = k >> 5, kr = k & 31;
            int lane = ((kr >> 3) << 4) | nr;
            T[((size_t)(kc * 21 + nt)) * 512 + lane * 8 + (k & 7)] = f2bf(s1);
        }
        {
            int kk = k + 512;
            int kc = kk >> 5, kr = kk & 31;
            int lane = ((kr >> 3) << 4) | nr;
            T[((size_t)(kc * 21 + nt)) * 512 + lane * 8 + (kk & 7)] = f2bf(s2);
        }
    } else {
        int h = (bid - 672) * 256 + tid;
        if (h >= H_) return;
        float acc = 0.f;
        for (int g = 0; g < FREQ_; ++g)
            acc += bm_re[g] * ctb[g * H_ + h] + bm_im[g] * stb[g * H_ + h];
        bvec[h] = acc;
    }
}

// ================= K1: fused LayerNorm, single x pass. grid (11, 32), 512 thr =
__global__ __launch_bounds__(512) void k_ln3(const float* __restrict__ x,
                                             unsigned short* __restrict__ fullbf,
                                             float* __restrict__ muv,
                                             float* __restrict__ nrm) {
    __shared__ float red_s[16][32], red_q[16][32];
    __shared__ float sMu[32], sInv[32];
    __shared__ float tl[64][33];
    int tid = threadIdx.x;
    int c_l = tid & 31, lg = tid >> 5;       // lg 0..15, each covers 32 l
    int b = blockIdx.y, c0 = blockIdx.x * 32;
    int c = c0 + c_l;
    bool valid = (c < C_);
    const float* xb = x + (size_t)b * L_ * C_;

    float s = 0.f, q = 0.f;
    #pragma unroll 8
    for (int i = 0; i < 32; ++i) {
        int l = lg * 32 + i;
        float v = valid ? xb[(size_t)l * C_ + c] : 0.f;
        s += v; q += v * v;
    }
    red_s[lg][c_l] = s; red_q[lg][c_l] = q;
    __syncthreads();
    if (tid < 32) {
        float S = 0.f, Q = 0.f;
        #pragma unroll
        for (int g = 0; g < 16; ++g) { S += red_s[g][tid]; Q += red_q[g][tid]; }
        float mu = S / (float)L_;
        float var = Q / (float)L_ - mu * mu;
        float n = sqrtf(var + EPS_);
        sMu[tid] = mu; sInv[tid] = 1.0f / n;
        if (c0 + tid < C_) {
            muv[(size_t)b * C_ + c0 + tid] = mu;
            nrm[(size_t)b * C_ + c0 + tid] = n;
        }
    }
    __syncthreads();
    float mu = sMu[c_l], inv = sInv[c_l];

    for (int l0 = 0; l0 < L_; l0 += 64) {
        for (int li = lg; li < 64; li += 16) {
            float v = valid ? xb[(size_t)(l0 + li) * C_ + c] : 0.f;
            tl[li][c_l] = (v - mu) * inv;
        }
        __syncthreads();
        #pragma unroll
        for (int t = 0; t < 2; ++t) {
            int idx = tid + t * 512;
            int cr = idx >> 5, j = idx & 31;
            int cc = c0 + cr;
            if (cc < C_) {
                size_t bc = (size_t)b * C_ + cc;
                unsigned pk = (unsigned)f2bf(tl[2 * j][cr]) |
                              ((unsigned)f2bf(tl[2 * j + 1][cr]) << 16);
                ((unsigned*)fullbf)[(bc * LHB_ + l0) / 2 + j] = pk;
            }
        }
        __syncthreads();
    }
}

// ================= K2: merged {y_hat GEMM (4-way N split) | p-softmax} =======
// bid < 1284: y_hat, bc0=(bid>>2)*32, quarter=bid&3. bid >= 1284: p2 (16 bc).
__global__ __launch_bounds__(256) void k_hp(const unsigned short* __restrict__ fullbf,
                                            const unsigned short* __restrict__ Wbsw,
                                            const float* __restrict__ bb,
                                            const float* __restrict__ r,
                                            const float* __restrict__ Wc,
                                            const float* __restrict__ bcv,
                                            unsigned short* __restrict__ fullbf_w,
                                            float* __restrict__ p_out) {
    __shared__ float WcS[8 * F_FEAT];
    __shared__ float rsS[16][8];
    __shared__ float bcS[8];
    int bid = blockIdx.x;
    int tid = threadIdx.x, w = tid >> 6, lane = tid & 63;

    if (bid < 1284) {
        // ---- y_hat GEMM, quarter N split (21 nt -> 6,5,5,5) ----
        int bc0 = (bid >> 2) * 32;
        int qt = bid & 3;
        const int NQ[4][5] = {{0, 2, 4, 5, 6},
                              {6, 8, 9, 10, 11},
                              {11, 13, 14, 15, 16},
                              {16, 18, 19, 20, 21}};
        int nt0 = NQ[qt][w];
        int ntn = NQ[qt][w + 1] - nt0;
        int r15 = lane & 15, kg = lane >> 4;
        f32x4 acc[2][2];
        #pragma unroll
        for (int mf = 0; mf < 2; ++mf)
            #pragma unroll
            for (int j = 0; j < 2; ++j) acc[mf][j] = (f32x4){0.f, 0.f, 0.f, 0.f};
        for (int kc = 0; kc < 16; ++kc) {
            short8v a[2];
            #pragma unroll
            for (int mf = 0; mf < 2; ++mf)
                a[mf] = *(const short8v*)(fullbf + ((size_t)(bc0 + mf * 16 + r15) * LHB_ + kc * 32 + kg * 8));
            #pragma unroll
            for (int j = 0; j < 2; ++j) {
                if (j >= ntn) continue;
                short8v bfr = *(const short8v*)(Wbsw + ((size_t)(kc * 21 + nt0 + j) * 512 + lane * 8));
                #pragma unroll
                for (int mf = 0; mf < 2; ++mf)
                    acc[mf][j] = __builtin_amdgcn_mfma_f32_16x16x32_bf16(a[mf], bfr, acc[mf][j], 0, 0, 0);
            }
        }
        #pragma unroll
        for (int mf = 0; mf < 2; ++mf)
            #pragma unroll
            for (int j = 0; j < 2; ++j) {
                if (j >= ntn) continue;
                int n_ = (nt0 + j) * 16 + r15;
                #pragma unroll
                for (int reg = 0; reg < 4; ++reg) {
                    int bc = bc0 + mf * 16 + kg * 4 + reg;
                    fullbf_w[(size_t)bc * LHB_ + L_ + n_] = f2bf(acc[mf][j][reg] + bb[n_]);
                }
            }
    } else {
        // ---- p softmax ----
        int bc0 = (bid - 1284) * 16;
        for (int i = tid; i < 8 * F_FEAT; i += 256) WcS[i] = Wc[i];
        if (tid < 8) bcS[tid] = bcv[tid];
        if (tid < 16) {
            int bc = bc0 + tid;
            const float* rr = r + (size_t)bc * K_;
            float a[8]; float m = 1.0f;
            #pragma unroll
            for (int k = 0; k < 8; ++k) { a[k] = fabsf(rr[k]); m = fmaxf(m, a[k]); }
            float Z = expf(1.0f - m);
            float e[8];
            #pragma unroll
            for (int k = 0; k < 8; ++k) { e[k] = expf(a[k] - m); Z += e[k]; }
            float inv = 1.0f / Z;
            #pragma unroll
            for (int k = 0; k < 8; ++k) rsS[tid][k] = e[k] * inv;
        }
        __syncthreads();

        for (int i = 0; i < 4; ++i) {
            int bcl = w * 4 + i;
            int bc = bc0 + bcl;
            const unsigned* xrow = (const unsigned*)(fullbf + (size_t)bc * LHB_);
            float acc[8] = {0.f, 0.f, 0.f, 0.f, 0.f, 0.f, 0.f, 0.f};
            #pragma unroll
            for (int t = 0; t < 4; ++t) {
                int j = lane + t * 64;
                unsigned v = xrow[j];
                float x0 = bf2f((unsigned short)(v & 0xffff));
                float x1 = bf2f((unsigned short)(v >> 16));
                #pragma unroll
                for (int s = 0; s < 8; ++s)
                    acc[s] += x0 * WcS[s * F_FEAT + 2 * j] + x1 * WcS[s * F_FEAT + 2 * j + 1];
            }
            if (lane < 8) {
                float xf = rsS[bcl][lane];
                #pragma unroll
                for (int s = 0; s < 8; ++s) acc[s] += xf * WcS[s * F_FEAT + L_ + lane];
            }
            #pragma unroll
            for (int s = 0; s < 8; ++s) {
                #pragma unroll
                for (int off = 32; off > 0; off >>= 1) acc[s] += __shfl_down(acc[s], off);
            }
            if (lane == 0) {
                float m = -1e30f;
                #pragma unroll
                for (int s = 0; s < 8; ++s) { acc[s] += bcS[s]; m = fmaxf(m, acc[s]); }
                float Z = 0.f; float e[8];
                #pragma unroll
                for (int s = 0; s < 8; ++s) { e[s] = expf(acc[s] - m); Z += e[s]; }
                float inv = 1.0f / Z;
                #pragma unroll
                for (int s = 0; s < 8; ++s) p_out[(size_t)bc * 8 + s] = e[s] * inv;
            }
        }
    }
}

// ================= K4: fused gather + DFT MFMA + filter-combine -> z =========
// XCD-aware bijective block swizzle (T1, m204 chunked formula): contiguous bc
// chunks per XCD so same-batch fullbf slabs stay L2-resident for the gather.
__global__ __launch_bounds__(512) void k_dftz2(const unsigned short* __restrict__ fullbf,
                                               const int* __restrict__ leader,
                                               const int* __restrict__ shiftp,
                                               const unsigned short* __restrict__ Tsw,
                                               const float* __restrict__ pbuf,
                                               const float4* __restrict__ stf4,
                                               const float2* __restrict__ stg3,
                                               unsigned short* __restrict__ zbf) {
    __shared__ unsigned short A[64 * 360];
    __shared__ float psL[DZB_][8];
    int tid = threadIdx.x, w = tid >> 6, lane = tid & 63;
    // bijective chunked XCD swizzle: orig -> swz
    int nblk = gridDim.x;
    int q = nblk >> 3, rmd = nblk & 7;
    int xcd = blockIdx.x & 7, sidx = blockIdx.x >> 3;
    int swz = (xcd < rmd) ? (xcd * (q + 1) + sidx)
                          : (rmd * (q + 1) + (xcd - rmd) * q + sidx);
    int bc0 = swz * DZB_;
    unsigned* A32 = (unsigned*)A;
    for (int i = tid; i < 64 * 180; i += 512) A32[i] = 0;
    if (tid < DZB_ * 8) {
        int bcl = tid >> 3, s = tid & 7;
        int bc = bc0 + bcl;
        psL[bcl][s] = (bc < BCN_) ? pbuf[(size_t)bc * 8 + s] : 0.f;
    }
    if (tid >= 64 && tid < 64 + DZB_ * 10) {
        int t = tid - 64;
        int bcl = t / 10, o = t - bcl * 10;
        int bc = bc0 + bcl;
        if (bc < BCN_) {
            unsigned short* zrow = zbf + (size_t)bc * 1024;
            if (o < 5) zrow[507 + o] = 0;
            else       zrow[1019 + (o - 5)] = 0;
        }
    }
    __syncthreads();

    #pragma unroll
    for (int i = 0; i < 8; ++i) {
        int rr = w * 8 + i;
        if (rr >= 63) break;
        int bcl = rr / 9, k = rr - bcl * 9;
        int bc = bc0 + bcl;
        if (bc < BCN_) {
            int b = bc / C_;
            const unsigned short* src;
            if (k < 8) {
                int lead = leader[(size_t)bc * K_ + k];
                int sh = shiftp[(size_t)bc * K_ + k];
                src = fullbf + ((size_t)b * C_ + lead) * LHB_ + (L_ - sh);
            } else {
                src = fullbf + (size_t)bc * LHB_ + L_;
            }
            unsigned short* dst = A + rr * 360;
            #pragma unroll
            for (int t = 0; t < 6; ++t) {
                int j = lane + t * 64;
                if (j < H_) dst[j] = src[j];
            }
        }
    }
    __syncthreads();

    const int NTB[9] = {0, 3, 6, 9, 11, 14, 17, 20, 22};
    int nt0 = NTB[w], ntn = NTB[w + 1] - nt0;
    int r15 = lane & 15, kg = lane >> 4;
    f32x4 acc[4][3];
    #pragma unroll
    for (int mf = 0; mf < 4; ++mf)
        #pragma unroll
        for (int j = 0; j < 3; ++j) acc[mf][j] = (f32x4){0.f, 0.f, 0.f, 0.f};
    for (int kc = 0; kc < 11; ++kc) {
        short8v a[4];
        #pragma unroll
        for (int mf = 0; mf < 4; ++mf)
            a[mf] = *(const short8v*)(A + (size_t)(mf * 16 + r15) * 360 + kc * 32 + kg * 8);
        #pragma unroll
        for (int j = 0; j < 3; ++j) {
            if (j >= ntn) continue;
            short8v bfr = *(const short8v*)(Tsw + ((size_t)(kc * 22 + nt0 + j) * 512 + lane * 8));
            #pragma unroll
            for (int mf = 0; mf < 4; ++mf)
                acc[mf][j] = __builtin_amdgcn_mfma_f32_16x16x32_bf16(a[mf], bfr, acc[mf][j], 0, 0, 0);
        }
    }
    __syncthreads();

    #pragma unroll
    for (int mf = 0; mf < 4; ++mf)
        #pragma unroll
        for (int j = 0; j < 3; ++j) {
            if (j >= ntn) continue;
            int col = (nt0 + j) * 16 + r15;
            #pragma unroll
            for (int reg = 0; reg < 4; ++reg) {
                int row = mf * 16 + kg * 4 + reg;
                A[row * 360 + col] = f2bf(acc[mf][j][reg]);
            }
        }
    __syncthreads();

    if (tid < 507) {
        int g = tid / 169;
        int f = tid - g * 169;
        int bclo = (g == 0) ? 0 : (g == 1) ? 3 : 5;
        int nb   = (g == 0) ? 3 : 2;
        float z1r[3], z1i[3], z2r[3], z2i[3], Yr[3], Yi[3];
        #pragma unroll
        for (int bl = 0; bl < 3; ++bl) {
            z1r[bl] = z1i[bl] = z2r[bl] = z2i[bl] = 0.f;
            unsigned v = (bl < nb) ? A32[((bclo + bl) * 9 + 8) * 180 + f] : 0u;
            Yr[bl] = bf2f((unsigned short)(v & 0xffff));
            Yi[bl] = bf2f((unsigned short)(v >> 16));
        }
        for (int k = 0; k < 8; ++k) {
            float4 stv[8];
            #pragma unroll
            for (int s = 0; s < 8; ++s) stv[s] = stf4[(size_t)(k * 8 + s) * FREQ_ + f];
            #pragma unroll
            for (int bl = 0; bl < 3; ++bl) {
                if (bl >= nb) continue;
                int bcl = bclo + bl;
                float f1r = 0.f, f1i = 0.f, f2r = 0.f, f2i = 0.f;
                #pragma unroll
                for (int s = 0; s < 8; ++s) {
                    float p = psL[bcl][s];
                    f1r += p * stv[s].x; f1i += p * stv[s].y;
                    f2r += p * stv[s].z; f2i += p * stv[s].w;
                }
                unsigned v = A32[(bcl * 9 + k) * 180 + f];
                float Xr = bf2f((unsigned short)(v & 0xffff));
                float Xi = bf2f((unsigned short)(v >> 16));
                float ar = Xr * f1r - Xi * f1i;
                float ai = Xr * f1i + Xi * f1r;
                z1r[bl] += ar; z1i[bl] += ai;
                float dr = ar - Yr[bl], di = ai - Yi[bl];
                z2r[bl] += dr * f2r - di * f2i;
                z2i[bl] += dr * f2i + di * f2r;
            }
        }
        #pragma unroll
        for (int bl = 0; bl < 3; ++bl) {
            if (bl >= nb) continue;
            int bcl = bclo + bl;
            int bc = bc0 + bcl;
            if (bc >= BCN_) continue;
            float f3r = 0.f, f3i = 0.f;
            #pragma unroll
            for (int s = 0; s < 8; ++s) {
                float2 v3 = stg3[(size_t)s * FREQ_ + f];
                float p = psL[bcl][s];
                f3r += p * v3.x; f3i += p * v3.y;
            }
            unsigned short* zrow = zbf + (size_t)bc * 1024;
            zrow[f]       = f2bf(z1r[bl]);  zrow[512 + f]       = f2bf(z1i[bl]);
            zrow[169 + f] = f2bf(z2r[bl]);  zrow[512 + 169 + f] = f2bf(z2i[bl]);
            zrow[338 + f] = f2bf(Yr[bl] * f3r - Yi[bl] * f3i);
            zrow[512 + 338 + f] = f2bf(Yr[bl] * f3i + Yi[bl] * f3r);
        }
    }
}

// ================= K6: fused (mix+irfft) GEMM + transposed store =============
// bc-tile 16 (grid 642 x 2) for occupancy; per-output arithmetic unchanged.
__global__ __launch_bounds__(256) void k_mixf2(const unsigned short* __restrict__ zbf,
                                               const unsigned short* __restrict__ WTsw,
                                               const float* __restrict__ bvec,
                                               const unsigned short* __restrict__ fullbf,
                                               const float* __restrict__ muv,
                                               const float* __restrict__ nrm,
                                               float* __restrict__ out) {
    __shared__ float ytile[16][177];
    int bc0 = blockIdx.x * 16;
    int half = blockIdx.y;
    int tid = threadIdx.x, w = tid >> 6, lane = tid & 63;
    const int NTB0[5] = {0, 3, 6, 9, 11};
    const int NTB1[5] = {11, 14, 17, 19, 21};
    int nt0 = half ? NTB1[w] : NTB0[w];
    int ntn = (half ? NTB1[w + 1] : NTB0[w + 1]) - nt0;
    int h0 = half ? 176 : 0;
    int hn = half ? 160 : 176;
    int r15 = lane & 15, kg = lane >> 4;
    f32x4 acc[3];
    #pragma unroll
    for (int j = 0; j < 3; ++j) acc[j] = (f32x4){0.f, 0.f, 0.f, 0.f};
    for (int kc = 0; kc < 32; ++kc) {
        short8v a = *(const short8v*)(zbf + ((size_t)(bc0 + r15) * 1024 + kc * 32 + kg * 8));
        #pragma unroll
        for (int j = 0; j < 3; ++j) {
            if (j >= ntn) continue;
            short8v bfr = *(const short8v*)(WTsw + ((size_t)(kc * 21 + nt0 + j) * 512 + lane * 8));
            acc[j] = __builtin_amdgcn_mfma_f32_16x16x32_bf16(a, bfr, acc[j], 0, 0, 0);
        }
    }
    #pragma unroll
    for (int j = 0; j < 3; ++j) {
        if (j >= ntn) continue;
        int h = (nt0 + j) * 16 + r15;
        float bv = bvec[h];
        #pragma unroll
        for (int reg = 0; reg < 4; ++reg) {
            int bcl = kg * 4 + reg;
            int bc = bc0 + bcl;
            float yh = bf2f(fullbf[(size_t)bc * LHB_ + L_ + h]);
            float y = (yh + acc[j][reg] + bv) * nrm[bc] + muv[bc];
            ytile[bcl][h - h0] = y;
        }
    }
    __syncthreads();
    for (int idx = tid; idx < 16 * hn; idx += 256) {
        int bcl = idx & 15, hrel = idx >> 4;
        int bc = bc0 + bcl;
        int b = bc / C_, c = bc - b * C_;
        out[((size_t)b * H_ + h0 + hrel) * C_ + c] = ytile[bcl][hrel];
    }
}

extern "C" void kernel_launch(void* const* d_in, const int* in_sizes, int n_in,
                              void* d_out, int out_size, void* d_ws, size_t ws_size,
                              hipStream_t stream) {
    const float* x     = (const float*)d_in[0];
    const float* r     = (const float*)d_in[1];
    const float* Wb    = (const float*)d_in[2];
    const float* bb    = (const float*)d_in[3];
    const float* Wc    = (const float*)d_in[4];
    const float* bcv   = (const float*)d_in[5];
    const float* st_re = (const float*)d_in[6];
    const float* st_im = (const float*)d_in[7];
    const float* Wm_re = (const float*)d_in[8];
    const float* Wm_im = (const float*)d_in[9];
    const float* bm_re = (const float*)d_in[10];
    const float* bm_im = (const float*)d_in[11];
    const int* leader  = (const int*)d_in[12];
    const int* shiftp  = (const int*)d_in[13];
    float* out = (float*)d_out;

    char* w = (char*)d_ws;
    auto carve = [&](size_t bytes) {
        char* p = w;
        w += (bytes + 255) & ~(size_t)255;
        return (void*)p;
    };
    unsigned short* Tdft = (unsigned short*)carve((size_t)11 * 22 * 512 * 2);
    unsigned short* WTsw = (unsigned short*)carve((size_t)32 * 21 * 512 * 2);
    unsigned short* Wbsw = (unsigned short*)carve((size_t)16 * 21 * 512 * 2);
    float*          ctb  = (float*)carve((size_t)FREQ_ * H_ * 4);
    float*          stb  = (float*)carve((size_t)FREQ_ * H_ * 4);
    float*          bvec = (float*)carve((size_t)H_ * 4);
    float4*         stf4 = (float4*)carve((size_t)64 * FREQ_ * 16);
    float2*         stg3 = (float2*)carve((size_t)8 * FREQ_ * 8);
    unsigned short* fullbf = (unsigned short*)carve((size_t)BCN_ * LHB_ * 2);
    float*          muv  = (float*)carve((size_t)BCN_ * 4);
    float*          nrm  = (float*)carve((size_t)BCN_ * 4);
    float*          pbuf = (float*)carve((size_t)BCN_ * 8 * 4);
    unsigned short* zbf  = (unsigned short*)carve((size_t)BCN_ * 1024 * 2);

    hipLaunchKernelGGL(k_prepA, dim3(410), dim3(256), 0, stream,
                       Wb, st_re, st_im, Tdft, ctb, stb, Wbsw, stf4, stg3);
    hipLaunchKernelGGL(k_prepB, dim3(674), dim3(256), 0, stream,
                       Wm_re, Wm_im, bm_re, bm_im, ctb, stb, WTsw, bvec);
    hipLaunchKernelGGL(k_ln3, dim3(11, 32), dim3(512), 0, stream, x, fullbf, muv, nrm);
    hipLaunchKernelGGL(k_hp, dim3(1284 + 642), dim3(256), 0, stream,
                       fullbf, Wbsw, bb, r, Wc, bcv, fullbf, pbuf);
    hipLaunchKernelGGL(k_dftz2, dim3((BCN_ + DZB_ - 1) / DZB_), dim3(512), 0, stream,
                       fullbf, leader, shiftp, Tdft, pbuf, stf4, stg3, zbf);
    hipLaunchKernelGGL(k_mixf2, dim3(BCN_ / 16, 2), dim3(256), 0, stream,
                       zbf, WTsw, bvec, fullbf, muv, nrm, out);
}

// Round 21
// 215.802 us; speedup vs baseline: 1.0408x; 1.0408x over previous
//
#include <hip/hip_runtime.h>
#include <math.h>

#define B_ 32
#define L_ 512
#define H_ 336
#define C_ 321
#define K_ 8
#define S_ 8
#define FREQ_ 169   // H/2+1
#define G_ 17       // 2K+1
#define LHB_ 848    // L+H (bf16 row length)
#define F_FEAT 520  // L+K
#define EPS_ 1e-5f
#define BCN_ (B_ * C_)    // 10272
#define DZB_ 7            // bc per k_dftz2 block (63 of 64 M-rows)

#ifndef M_PIf
#define M_PIf 3.14159265358979323846f
#endif

typedef __attribute__((ext_vector_type(8))) short short8v;
typedef __attribute__((ext_vector_type(4))) float f32x4;

__device__ __forceinline__ unsigned short f2bf(float x) {
    unsigned u = __builtin_bit_cast(unsigned, x);
    u += 0x7FFFu + ((u >> 16) & 1u);
    return (unsigned short)(u >> 16);
}
__device__ __forceinline__ float bf2f(unsigned short h) {
    return __builtin_bit_cast(float, (unsigned)h << 16);
}

// ================= merged prep A: {Tdft, ctb/stb, Wbsw, stf4/stg3} ===========
// Fragment layout (16x16x32 bf16): b-frag lane l holds B[kc*32 + (l>>4)*8 + i][nt*16 + (l&15)].
__global__ __launch_bounds__(256) void k_prepA(const float* __restrict__ Wb,
                                               const float* __restrict__ st_re,
                                               const float* __restrict__ st_im,
                                               unsigned short* __restrict__ Tdft,
                                               float* __restrict__ ctb,
                                               float* __restrict__ stb,
                                               unsigned short* __restrict__ Wbsw,
                                               float4* __restrict__ stf4,
                                               float2* __restrict__ stg3) {
    int bid = blockIdx.x, tid = threadIdx.x;
    if (bid < 61) {
        // DFT table: 242 logical 64-thr blocks
        int orig = bid * 4 + (tid >> 6);
        if (orig < 11 * 22) {
            int lane = tid & 63;
            int kc = orig / 22, nt = orig % 22;
            int n = nt * 16 + (lane & 15);
            int kb = kc * 32 + (lane >> 4) * 8;
            int f = n >> 1;
            unsigned short* dst = Tdft + (size_t)orig * 512 + lane * 8;
            for (int i = 0; i < 8; ++i) {
                int k = kb + i;
                float val = 0.f;
                if (k < H_ && n < 2 * FREQ_) {
                    int m = (k * f) % H_;
                    float s, c;
                    sincosf((float)m * (2.0f * M_PIf / (float)H_), &s, &c);
                    val = (n & 1) ? -s : c;
                }
                dst[i] = f2bf(val);
            }
        }
    } else if (bid < 283) {
        // weighted twiddle tables
        int idx = (bid - 61) * 256 + tid;
        if (idx < FREQ_ * H_) {
            int g = idx / H_, h = idx % H_;
            int m = (g * h) % H_;
            float s, c;
            sincosf((float)m * (2.0f * M_PIf / (float)H_), &s, &c);
            float wgt = ((g == 0 || g == FREQ_ - 1) ? 1.0f : 2.0f) * (1.0f / (float)H_);
            ctb[idx] = wgt * c;
            stb[idx] = -wgt * s;
        }
    } else if (bid < 367) {
        // Wb swizzle: 336 logical 64-thr blocks
        int orig = (bid - 283) * 4 + (tid >> 6);
        if (orig < 16 * 21) {
            int lane = tid & 63;
            int kc = orig / 21, nt = orig % 21;
            int n = nt * 16 + (lane & 15);
            int kb = kc * 32 + (lane >> 4) * 8;
            unsigned short* dst = Wbsw + (size_t)orig * 512 + lane * 8;
            for (int i = 0; i < 8; ++i) {
                int k = kb + i;
                dst[i] = f2bf(Wb[(size_t)n * L_ + k]);
            }
        }
    } else {
        // states repack
        int idx = (bid - 367) * 256 + tid;
        if (idx < 64 * FREQ_) {
            int row = idx / FREQ_, f = idx % FREQ_;
            int k = row >> 3, s = row & 7;
            size_t b1 = (size_t)s * (G_ * FREQ_) + (size_t)k * FREQ_ + f;
            size_t b2 = (size_t)s * (G_ * FREQ_) + (size_t)(8 + k) * FREQ_ + f;
            stf4[idx] = make_float4(st_re[b1], st_im[b1], st_re[b2], st_im[b2]);
        }
        if (idx < 8 * FREQ_) {
            int s = idx / FREQ_, f = idx % FREQ_;
            size_t b3 = (size_t)s * (G_ * FREQ_) + (size_t)16 * FREQ_ + f;
            stg3[idx] = make_float2(st_re[b3], st_im[b3]);
        }
    }
}

// ================= merged prep B: {WTsw, bvec} (needs ctb/stb) ===============
__global__ __launch_bounds__(256) void k_prepB(const float* __restrict__ Wm_re,
                                               const float* __restrict__ Wm_im,
                                               const float* __restrict__ bm_re,
                                               const float* __restrict__ bm_im,
                                               const float* __restrict__ ctb,
                                               const float* __restrict__ stb,
                                               unsigned short* __restrict__ T,
                                               float* __restrict__ bvec) {
    int bid = blockIdx.x, tid = threadIdx.x;
    if (bid < 672) {
        int t = bid * 256 + tid;
        if (t >= 512 * H_) return;
        int k = t / H_, h = t - k * H_;
        float s1 = 0.f, s2 = 0.f;
        if (k < 3 * FREQ_) {
            #pragma unroll 4
            for (int g = 0; g < FREQ_; ++g) {
                float ct = ctb[g * H_ + h];
                float st = stb[g * H_ + h];
                float wr = Wm_re[(size_t)g * (3 * FREQ_) + k];
                float wi = Wm_im[(size_t)g * (3 * FREQ_) + k];
                s1 += wr * ct + wi * st;
                s2 += wr * st - wi * ct;
            }
        }
        int nt = h >> 4, nr = h & 15;
        {
            int kc = k >> 5, kr = k & 31;
            int lane = ((kr >> 3) << 4) | nr;
            T[((size_t)(kc * 21 + nt)) * 512 + lane * 8 + (k & 7)] = f2bf(s1);
        }
        {
            int kk = k + 512;
            int kc = kk >> 5, kr = kk & 31;
            int lane = ((kr >> 3) << 4) | nr;
            T[((size_t)(kc * 21 + nt)) * 512 + lane * 8 + (kk & 7)] = f2bf(s2);
        }
    } else {
        int h = (bid - 672) * 256 + tid;
        if (h >= H_) return;
        float acc = 0.f;
        for (int g = 0; g < FREQ_; ++g)
            acc += bm_re[g] * ctb[g * H_ + h] + bm_im[g] * stb[g * H_ + h];
        bvec[h] = acc;
    }
}

// ================= K1: fused LayerNorm, single x pass. grid (11, 32), 512 thr =
// Phase 1: stream 32c x 512l slice (coalesced), LDS-reduce -> mu/inv.
// Phase 2: re-read slice (L2-hot), normalize, LDS-transpose, write bf16.
__global__ __launch_bounds__(512) void k_ln3(const float* __restrict__ x,
                                             unsigned short* __restrict__ fullbf,
                                             float* __restrict__ muv,
                                             float* __restrict__ nrm) {
    __shared__ float red_s[16][32], red_q[16][32];
    __shared__ float sMu[32], sInv[32];
    __shared__ float tl[64][33];
    int tid = threadIdx.x;
    int c_l = tid & 31, lg = tid >> 5;       // lg 0..15, each covers 32 l
    int b = blockIdx.y, c0 = blockIdx.x * 32;
    int c = c0 + c_l;
    bool valid = (c < C_);
    const float* xb = x + (size_t)b * L_ * C_;

    float s = 0.f, q = 0.f;
    #pragma unroll 8
    for (int i = 0; i < 32; ++i) {
        int l = lg * 32 + i;
        float v = valid ? xb[(size_t)l * C_ + c] : 0.f;
        s += v; q += v * v;
    }
    red_s[lg][c_l] = s; red_q[lg][c_l] = q;
    __syncthreads();
    if (tid < 32) {
        float S = 0.f, Q = 0.f;
        #pragma unroll
        for (int g = 0; g < 16; ++g) { S += red_s[g][tid]; Q += red_q[g][tid]; }
        float mu = S / (float)L_;
        float var = Q / (float)L_ - mu * mu;
        float n = sqrtf(var + EPS_);
        sMu[tid] = mu; sInv[tid] = 1.0f / n;
        if (c0 + tid < C_) {
            muv[(size_t)b * C_ + c0 + tid] = mu;
            nrm[(size_t)b * C_ + c0 + tid] = n;
        }
    }
    __syncthreads();
    float mu = sMu[c_l], inv = sInv[c_l];

    for (int l0 = 0; l0 < L_; l0 += 64) {
        for (int li = lg; li < 64; li += 16) {
            float v = valid ? xb[(size_t)(l0 + li) * C_ + c] : 0.f;
            tl[li][c_l] = (v - mu) * inv;
        }
        __syncthreads();
        #pragma unroll
        for (int t = 0; t < 2; ++t) {
            int idx = tid + t * 512;
            int cr = idx >> 5, j = idx & 31;
            int cc = c0 + cr;
            if (cc < C_) {
                size_t bc = (size_t)b * C_ + cc;
                unsigned pk = (unsigned)f2bf(tl[2 * j][cr]) |
                              ((unsigned)f2bf(tl[2 * j + 1][cr]) << 16);
                ((unsigned*)fullbf)[(bc * LHB_ + l0) / 2 + j] = pk;
            }
        }
        __syncthreads();
    }
}

// ================= K2: merged {y_hat GEMM | p-softmax} =======================
// bid < 642: y_hat via MFMA (bc-tile 32, N half split). bid >= 642: p2 (16 bc).
__global__ __launch_bounds__(256) void k_hp(const unsigned short* __restrict__ fullbf,
                                            const unsigned short* __restrict__ Wbsw,
                                            const float* __restrict__ bb,
                                            const float* __restrict__ r,
                                            const float* __restrict__ Wc,
                                            const float* __restrict__ bcv,
                                            unsigned short* __restrict__ fullbf_w,
                                            float* __restrict__ p_out) {
    __shared__ float WcS[8 * F_FEAT];
    __shared__ float rsS[16][8];
    __shared__ float bcS[8];
    int bid = blockIdx.x;
    int tid = threadIdx.x, w = tid >> 6, lane = tid & 63;

    if (bid < 642) {
        // ---- y_hat GEMM ----
        int bc0 = (bid >> 1) * 32;
        int half = bid & 1;
        const int NTB0[5] = {0, 3, 6, 9, 11};
        const int NTB1[5] = {11, 14, 17, 19, 21};
        int nt0 = half ? NTB1[w] : NTB0[w];
        int ntn = (half ? NTB1[w + 1] : NTB0[w + 1]) - nt0;
        int r15 = lane & 15, kg = lane >> 4;
        f32x4 acc[2][3];
        #pragma unroll
        for (int mf = 0; mf < 2; ++mf)
            #pragma unroll
            for (int j = 0; j < 3; ++j) acc[mf][j] = (f32x4){0.f, 0.f, 0.f, 0.f};
        for (int kc = 0; kc < 16; ++kc) {
            short8v a[2];
            #pragma unroll
            for (int mf = 0; mf < 2; ++mf)
                a[mf] = *(const short8v*)(fullbf + ((size_t)(bc0 + mf * 16 + r15) * LHB_ + kc * 32 + kg * 8));
            #pragma unroll
            for (int j = 0; j < 3; ++j) {
                if (j >= ntn) continue;
                short8v bfr = *(const short8v*)(Wbsw + ((size_t)(kc * 21 + nt0 + j) * 512 + lane * 8));
                #pragma unroll
                for (int mf = 0; mf < 2; ++mf)
                    acc[mf][j] = __builtin_amdgcn_mfma_f32_16x16x32_bf16(a[mf], bfr, acc[mf][j], 0, 0, 0);
            }
        }
        #pragma unroll
        for (int mf = 0; mf < 2; ++mf)
            #pragma unroll
            for (int j = 0; j < 3; ++j) {
                if (j >= ntn) continue;
                int n_ = (nt0 + j) * 16 + r15;
                #pragma unroll
                for (int reg = 0; reg < 4; ++reg) {
                    int bc = bc0 + mf * 16 + kg * 4 + reg;
                    fullbf_w[(size_t)bc * LHB_ + L_ + n_] = f2bf(acc[mf][j][reg] + bb[n_]);
                }
            }
    } else {
        // ---- p softmax ----
        int bc0 = (bid - 642) * 16;
        for (int i = tid; i < 8 * F_FEAT; i += 256) WcS[i] = Wc[i];
        if (tid < 8) bcS[tid] = bcv[tid];
        if (tid < 16) {
            int bc = bc0 + tid;
            const float* rr = r + (size_t)bc * K_;
            float a[8]; float m = 1.0f;
            #pragma unroll
            for (int k = 0; k < 8; ++k) { a[k] = fabsf(rr[k]); m = fmaxf(m, a[k]); }
            float Z = expf(1.0f - m);
            float e[8];
            #pragma unroll
            for (int k = 0; k < 8; ++k) { e[k] = expf(a[k] - m); Z += e[k]; }
            float inv = 1.0f / Z;
            #pragma unroll
            for (int k = 0; k < 8; ++k) rsS[tid][k] = e[k] * inv;
        }
        __syncthreads();

        for (int i = 0; i < 4; ++i) {
            int bcl = w * 4 + i;
            int bc = bc0 + bcl;
            const unsigned* xrow = (const unsigned*)(fullbf + (size_t)bc * LHB_);
            float acc[8] = {0.f, 0.f, 0.f, 0.f, 0.f, 0.f, 0.f, 0.f};
            #pragma unroll
            for (int t = 0; t < 4; ++t) {
                int j = lane + t * 64;
                unsigned v = xrow[j];
                float x0 = bf2f((unsigned short)(v & 0xffff));
                float x1 = bf2f((unsigned short)(v >> 16));
                #pragma unroll
                for (int s = 0; s < 8; ++s)
                    acc[s] += x0 * WcS[s * F_FEAT + 2 * j] + x1 * WcS[s * F_FEAT + 2 * j + 1];
            }
            if (lane < 8) {
                float xf = rsS[bcl][lane];
                #pragma unroll
                for (int s = 0; s < 8; ++s) acc[s] += xf * WcS[s * F_FEAT + L_ + lane];
            }
            #pragma unroll
            for (int s = 0; s < 8; ++s) {
                #pragma unroll
                for (int off = 32; off > 0; off >>= 1) acc[s] += __shfl_down(acc[s], off);
            }
            if (lane == 0) {
                float m = -1e30f;
                #pragma unroll
                for (int s = 0; s < 8; ++s) { acc[s] += bcS[s]; m = fmaxf(m, acc[s]); }
                float Z = 0.f; float e[8];
                #pragma unroll
                for (int s = 0; s < 8; ++s) { e[s] = expf(acc[s] - m); Z += e[s]; }
                float inv = 1.0f / Z;
                #pragma unroll
                for (int s = 0; s < 8; ++s) p_out[(size_t)bc * 8 + s] = e[s] * inv;
            }
        }
    }
}

// ================= K4: fused gather + DFT MFMA + filter-combine -> z =========
// XCD-aware bijective block swizzle (T1, m204 chunked formula): contiguous bc
// chunks per XCD so same-batch fullbf slabs stay L2-resident for the gather.
__global__ __launch_bounds__(512) void k_dftz2(const unsigned short* __restrict__ fullbf,
                                               const int* __restrict__ leader,
                                               const int* __restrict__ shiftp,
                                               const unsigned short* __restrict__ Tsw,
                                               const float* __restrict__ pbuf,
                                               const float4* __restrict__ stf4,
                                               const float2* __restrict__ stg3,
                                               unsigned short* __restrict__ zbf) {
    __shared__ unsigned short A[64 * 360];
    __shared__ float psL[DZB_][8];
    int tid = threadIdx.x, w = tid >> 6, lane = tid & 63;
    // bijective chunked XCD swizzle: orig -> swz
    int nblk = gridDim.x;
    int q = nblk >> 3, rmd = nblk & 7;
    int xcd = blockIdx.x & 7, sidx = blockIdx.x >> 3;
    int swz = (xcd < rmd) ? (xcd * (q + 1) + sidx)
                          : (rmd * (q + 1) + (xcd - rmd) * q + sidx);
    int bc0 = swz * DZB_;
    unsigned* A32 = (unsigned*)A;
    for (int i = tid; i < 64 * 180; i += 512) A32[i] = 0;
    if (tid < DZB_ * 8) {
        int bcl = tid >> 3, s = tid & 7;
        int bc = bc0 + bcl;
        psL[bcl][s] = (bc < BCN_) ? pbuf[(size_t)bc * 8 + s] : 0.f;
    }
    if (tid >= 64 && tid < 64 + DZB_ * 10) {
        int t = tid - 64;
        int bcl = t / 10, o = t - bcl * 10;
        int bc = bc0 + bcl;
        if (bc < BCN_) {
            unsigned short* zrow = zbf + (size_t)bc * 1024;
            if (o < 5) zrow[507 + o] = 0;
            else       zrow[1019 + (o - 5)] = 0;
        }
    }
    __syncthreads();

    #pragma unroll
    for (int i = 0; i < 8; ++i) {
        int rr = w * 8 + i;
        if (rr >= 63) break;
        int bcl = rr / 9, k = rr - bcl * 9;
        int bc = bc0 + bcl;
        if (bc < BCN_) {
            int b = bc / C_;
            const unsigned short* src;
            if (k < 8) {
                int lead = leader[(size_t)bc * K_ + k];
                int sh = shiftp[(size_t)bc * K_ + k];
                src = fullbf + ((size_t)b * C_ + lead) * LHB_ + (L_ - sh);
            } else {
                src = fullbf + (size_t)bc * LHB_ + L_;
            }
            unsigned short* dst = A + rr * 360;
            #pragma unroll
            for (int t = 0; t < 6; ++t) {
                int j = lane + t * 64;
                if (j < H_) dst[j] = src[j];
            }
        }
    }
    __syncthreads();

    const int NTB[9] = {0, 3, 6, 9, 11, 14, 17, 20, 22};
    int nt0 = NTB[w], ntn = NTB[w + 1] - nt0;
    int r15 = lane & 15, kg = lane >> 4;
    f32x4 acc[4][3];
    #pragma unroll
    for (int mf = 0; mf < 4; ++mf)
        #pragma unroll
        for (int j = 0; j < 3; ++j) acc[mf][j] = (f32x4){0.f, 0.f, 0.f, 0.f};
    for (int kc = 0; kc < 11; ++kc) {
        short8v a[4];
        #pragma unroll
        for (int mf = 0; mf < 4; ++mf)
            a[mf] = *(const short8v*)(A + (size_t)(mf * 16 + r15) * 360 + kc * 32 + kg * 8);
        #pragma unroll
        for (int j = 0; j < 3; ++j) {
            if (j >= ntn) continue;
            short8v bfr = *(const short8v*)(Tsw + ((size_t)(kc * 22 + nt0 + j) * 512 + lane * 8));
            #pragma unroll
            for (int mf = 0; mf < 4; ++mf)
                acc[mf][j] = __builtin_amdgcn_mfma_f32_16x16x32_bf16(a[mf], bfr, acc[mf][j], 0, 0, 0);
        }
    }
    __syncthreads();

    #pragma unroll
    for (int mf = 0; mf < 4; ++mf)
        #pragma unroll
        for (int j = 0; j < 3; ++j) {
            if (j >= ntn) continue;
            int col = (nt0 + j) * 16 + r15;
            #pragma unroll
            for (int reg = 0; reg < 4; ++reg) {
                int row = mf * 16 + kg * 4 + reg;
                A[row * 360 + col] = f2bf(acc[mf][j][reg]);
            }
        }
    __syncthreads();

    if (tid < 507) {
        int g = tid / 169;
        int f = tid - g * 169;
        int bclo = (g == 0) ? 0 : (g == 1) ? 3 : 5;
        int nb   = (g == 0) ? 3 : 2;
        float z1r[3], z1i[3], z2r[3], z2i[3], Yr[3], Yi[3];
        #pragma unroll
        for (int bl = 0; bl < 3; ++bl) {
            z1r[bl] = z1i[bl] = z2r[bl] = z2i[bl] = 0.f;
            unsigned v = (bl < nb) ? A32[((bclo + bl) * 9 + 8) * 180 + f] : 0u;
            Yr[bl] = bf2f((unsigned short)(v & 0xffff));
            Yi[bl] = bf2f((unsigned short)(v >> 16));
        }
        for (int k = 0; k < 8; ++k) {
            float4 stv[8];
            #pragma unroll
            for (int s = 0; s < 8; ++s) stv[s] = stf4[(size_t)(k * 8 + s) * FREQ_ + f];
            #pragma unroll
            for (int bl = 0; bl < 3; ++bl) {
                if (bl >= nb) continue;
                int bcl = bclo + bl;
                float f1r = 0.f, f1i = 0.f, f2r = 0.f, f2i = 0.f;
                #pragma unroll
                for (int s = 0; s < 8; ++s) {
                    float p = psL[bcl][s];
                    f1r += p * stv[s].x; f1i += p * stv[s].y;
                    f2r += p * stv[s].z; f2i += p * stv[s].w;
                }
                unsigned v = A32[(bcl * 9 + k) * 180 + f];
                float Xr = bf2f((unsigned short)(v & 0xffff));
                float Xi = bf2f((unsigned short)(v >> 16));
                float ar = Xr * f1r - Xi * f1i;
                float ai = Xr * f1i + Xi * f1r;
                z1r[bl] += ar; z1i[bl] += ai;
                float dr = ar - Yr[bl], di = ai - Yi[bl];
                z2r[bl] += dr * f2r - di * f2i;
                z2i[bl] += dr * f2i + di * f2r;
            }
        }
        #pragma unroll
        for (int bl = 0; bl < 3; ++bl) {
            if (bl >= nb) continue;
            int bcl = bclo + bl;
            int bc = bc0 + bcl;
            if (bc >= BCN_) continue;
            float f3r = 0.f, f3i = 0.f;
            #pragma unroll
            for (int s = 0; s < 8; ++s) {
                float2 v3 = stg3[(size_t)s * FREQ_ + f];
                float p = psL[bcl][s];
                f3r += p * v3.x; f3i += p * v3.y;
            }
            unsigned short* zrow = zbf + (size_t)bc * 1024;
            zrow[f]       = f2bf(z1r[bl]);  zrow[512 + f]       = f2bf(z1i[bl]);
            zrow[169 + f] = f2bf(z2r[bl]);  zrow[512 + 169 + f] = f2bf(z2i[bl]);
            zrow[338 + f] = f2bf(Yr[bl] * f3r - Yi[bl] * f3i);
            zrow[512 + 338 + f] = f2bf(Yr[bl] * f3i + Yi[bl] * f3r);
        }
    }
}

// ================= K6: fused (mix+irfft) GEMM + transposed store =============
// y_add = z @ WT + bvec; y_hat read as bf16 from fullbf; denorm; store out.
__global__ __launch_bounds__(256) void k_mixf2(const unsigned short* __restrict__ zbf,
                                               const unsigned short* __restrict__ WTsw,
                                               const float* __restrict__ bvec,
                                               const unsigned short* __restrict__ fullbf,
                                               const float* __restrict__ muv,
                                               const float* __restrict__ nrm,
                                               float* __restrict__ out) {
    __shared__ float ytile[32][177];
    int bc0 = blockIdx.x * 32;
    int half = blockIdx.y;
    int tid = threadIdx.x, w = tid >> 6, lane = tid & 63;
    const int NTB0[5] = {0, 3, 6, 9, 11};
    const int NTB1[5] = {11, 14, 17, 19, 21};
    int nt0 = half ? NTB1[w] : NTB0[w];
    int ntn = (half ? NTB1[w + 1] : NTB0[w + 1]) - nt0;
    int h0 = half ? 176 : 0;
    int hn = half ? 160 : 176;
    int r15 = lane & 15, kg = lane >> 4;
    f32x4 acc[2][3];
    #pragma unroll
    for (int mf = 0; mf < 2; ++mf)
        #pragma unroll
        for (int j = 0; j < 3; ++j) acc[mf][j] = (f32x4){0.f, 0.f, 0.f, 0.f};
    for (int kc = 0; kc < 32; ++kc) {
        short8v a[2];
        #pragma unroll
        for (int mf = 0; mf < 2; ++mf)
            a[mf] = *(const short8v*)(zbf + ((size_t)(bc0 + mf * 16 + r15) * 1024 + kc * 32 + kg * 8));
        #pragma unroll
        for (int j = 0; j < 3; ++j) {
            if (j >= ntn) continue;
            short8v bfr = *(const short8v*)(WTsw + ((size_t)(kc * 21 + nt0 + j) * 512 + lane * 8));
            #pragma unroll
            for (int mf = 0; mf < 2; ++mf)
                acc[mf][j] = __builtin_amdgcn_mfma_f32_16x16x32_bf16(a[mf], bfr, acc[mf][j], 0, 0, 0);
        }
    }
    #pragma unroll
    for (int mf = 0; mf < 2; ++mf)
        #pragma unroll
        for (int j = 0; j < 3; ++j) {
            if (j >= ntn) continue;
            int h = (nt0 + j) * 16 + r15;
            float bv = bvec[h];
            #pragma unroll
            for (int reg = 0; reg < 4; ++reg) {
                int bcl = mf * 16 + kg * 4 + reg;
                int bc = bc0 + bcl;
                float yh = bf2f(fullbf[(size_t)bc * LHB_ + L_ + h]);
                float y = (yh + acc[mf][j][reg] + bv) * nrm[bc] + muv[bc];
                ytile[bcl][h - h0] = y;
            }
        }
    __syncthreads();
    for (int idx = tid; idx < 32 * hn; idx += 256) {
        int bcl = idx & 31, hrel = idx >> 5;
        int bc = bc0 + bcl;
        int b = bc / C_, c = bc - b * C_;
        out[((size_t)b * H_ + h0 + hrel) * C_ + c] = ytile[bcl][hrel];
    }
}

extern "C" void kernel_launch(void* const* d_in, const int* in_sizes, int n_in,
                              void* d_out, int out_size, void* d_ws, size_t ws_size,
                              hipStream_t stream) {
    const float* x     = (const float*)d_in[0];
    const float* r     = (const float*)d_in[1];
    const float* Wb    = (const float*)d_in[2];
    const float* bb    = (const float*)d_in[3];
    const float* Wc    = (const float*)d_in[4];
    const float* bcv   = (const float*)d_in[5];
    const float* st_re = (const float*)d_in[6];
    const float* st_im = (const float*)d_in[7];
    const float* Wm_re = (const float*)d_in[8];
    const float* Wm_im = (const float*)d_in[9];
    const float* bm_re = (const float*)d_in[10];
    const float* bm_im = (const float*)d_in[11];
    const int* leader  = (const int*)d_in[12];
    const int* shiftp  = (const int*)d_in[13];
    float* out = (float*)d_out;

    char* w = (char*)d_ws;
    auto carve = [&](size_t bytes) {
        char* p = w;
        w += (bytes + 255) & ~(size_t)255;
        return (void*)p;
    };
    unsigned short* Tdft = (unsigned short*)carve((size_t)11 * 22 * 512 * 2);
    unsigned short* WTsw = (unsigned short*)carve((size_t)32 * 21 * 512 * 2);
    unsigned short* Wbsw = (unsigned short*)carve((size_t)16 * 21 * 512 * 2);
    float*          ctb  = (float*)carve((size_t)FREQ_ * H_ * 4);
    float*          stb  = (float*)carve((size_t)FREQ_ * H_ * 4);
    float*          bvec = (float*)carve((size_t)H_ * 4);
    float4*         stf4 = (float4*)carve((size_t)64 * FREQ_ * 16);
    float2*         stg3 = (float2*)carve((size_t)8 * FREQ_ * 8);
    unsigned short* fullbf = (unsigned short*)carve((size_t)BCN_ * LHB_ * 2);
    float*          muv  = (float*)carve((size_t)BCN_ * 4);
    float*          nrm  = (float*)carve((size_t)BCN_ * 4);
    float*          pbuf = (float*)carve((size_t)BCN_ * 8 * 4);
    unsigned short* zbf  = (unsigned short*)carve((size_t)BCN_ * 1024 * 2);

    hipLaunchKernelGGL(k_prepA, dim3(410), dim3(256), 0, stream,
                       Wb, st_re, st_im, Tdft, ctb, stb, Wbsw, stf4, stg3);
    hipLaunchKernelGGL(k_prepB, dim3(674), dim3(256), 0, stream,
                       Wm_re, Wm_im, bm_re, bm_im, ctb, stb, WTsw, bvec);
    hipLaunchKernelGGL(k_ln3, dim3(11, 32), dim3(512), 0, stream, x, fullbf, muv, nrm);
    hipLaunchKernelGGL(k_hp, dim3(642 + 642), dim3(256), 0, stream,
                       fullbf, Wbsw, bb, r, Wc, bcv, fullbf, pbuf);
    hipLaunchKernelGGL(k_dftz2, dim3((BCN_ + DZB_ - 1) / DZB_), dim3(512), 0, stream,
                       fullbf, leader, shiftp, Tdft, pbuf, stf4, stg3, zbf);
    hipLaunchKernelGGL(k_mixf2, dim3(BCN_ / 32, 2), dim3(256), 0, stream,
                       zbf, WTsw, bvec, fullbf, muv, nrm, out);
}

// Round 23
// 215.724 us; speedup vs baseline: 1.0412x; 1.0004x over previous
//
#include <hip/hip_runtime.h>
#include <math.h>

#define B_ 32
#define L_ 512
#define H_ 336
#define C_ 321
#define K_ 8
#define S_ 8
#define FREQ_ 169   // H/2+1
#define G_ 17       // 2K+1
#define LHB_ 848    // L+H (bf16 row length)
#define F_FEAT 520  // L+K
#define EPS_ 1e-5f
#define BCN_ (B_ * C_)    // 10272
#define DZB_ 7            // bc per k_dftz2 block (63 of 64 M-rows)

#ifndef M_PIf
#define M_PIf 3.14159265358979323846f
#endif

typedef __attribute__((ext_vector_type(8))) short short8v;
typedef __attribute__((ext_vector_type(4))) float f32x4;

__device__ __forceinline__ unsigned short f2bf(float x) {
    unsigned u = __builtin_bit_cast(unsigned, x);
    u += 0x7FFFu + ((u >> 16) & 1u);
    return (unsigned short)(u >> 16);
}
__device__ __forceinline__ float bf2f(unsigned short h) {
    return __builtin_bit_cast(float, (unsigned)h << 16);
}

// ================= merged prep A: {Tdft, ctb/stb, Wbsw, stf4/stg3} ===========
// Fragment layout (16x16x32 bf16): b-frag lane l holds B[kc*32 + (l>>4)*8 + i][nt*16 + (l&15)].
__global__ __launch_bounds__(256) void k_prepA(const float* __restrict__ Wb,
                                               const float* __restrict__ st_re,
                                               const float* __restrict__ st_im,
                                               unsigned short* __restrict__ Tdft,
                                               float* __restrict__ ctb,
                                               float* __restrict__ stb,
                                               unsigned short* __restrict__ Wbsw,
                                               float4* __restrict__ stf4,
                                               float2* __restrict__ stg3) {
    int bid = blockIdx.x, tid = threadIdx.x;
    if (bid < 61) {
        // DFT table: 242 logical 64-thr blocks
        int orig = bid * 4 + (tid >> 6);
        if (orig < 11 * 22) {
            int lane = tid & 63;
            int kc = orig / 22, nt = orig % 22;
            int n = nt * 16 + (lane & 15);
            int kb = kc * 32 + (lane >> 4) * 8;
            int f = n >> 1;
            unsigned short* dst = Tdft + (size_t)orig * 512 + lane * 8;
            for (int i = 0; i < 8; ++i) {
                int k = kb + i;
                float val = 0.f;
                if (k < H_ && n < 2 * FREQ_) {
                    int m = (k * f) % H_;
                    float s, c;
                    sincosf((float)m * (2.0f * M_PIf / (float)H_), &s, &c);
                    val = (n & 1) ? -s : c;
                }
                dst[i] = f2bf(val);
            }
        }
    } else if (bid < 283) {
        // weighted twiddle tables
        int idx = (bid - 61) * 256 + tid;
        if (idx < FREQ_ * H_) {
            int g = idx / H_, h = idx % H_;
            int m = (g * h) % H_;
            float s, c;
            sincosf((float)m * (2.0f * M_PIf / (float)H_), &s, &c);
            float wgt = ((g == 0 || g == FREQ_ - 1) ? 1.0f : 2.0f) * (1.0f / (float)H_);
            ctb[idx] = wgt * c;
            stb[idx] = -wgt * s;
        }
    } else if (bid < 367) {
        // Wb swizzle: 336 logical 64-thr blocks
        int orig = (bid - 283) * 4 + (tid >> 6);
        if (orig < 16 * 21) {
            int lane = tid & 63;
            int kc = orig / 21, nt = orig % 21;
            int n = nt * 16 + (lane & 15);
            int kb = kc * 32 + (lane >> 4) * 8;
            unsigned short* dst = Wbsw + (size_t)orig * 512 + lane * 8;
            for (int i = 0; i < 8; ++i) {
                int k = kb + i;
                dst[i] = f2bf(Wb[(size_t)n * L_ + k]);
            }
        }
    } else {
        // states repack
        int idx = (bid - 367) * 256 + tid;
        if (idx < 64 * FREQ_) {
            int row = idx / FREQ_, f = idx % FREQ_;
            int k = row >> 3, s = row & 7;
            size_t b1 = (size_t)s * (G_ * FREQ_) + (size_t)k * FREQ_ + f;
            size_t b2 = (size_t)s * (G_ * FREQ_) + (size_t)(8 + k) * FREQ_ + f;
            stf4[idx] = make_float4(st_re[b1], st_im[b1], st_re[b2], st_im[b2]);
        }
        if (idx < 8 * FREQ_) {
            int s = idx / FREQ_, f = idx % FREQ_;
            size_t b3 = (size_t)s * (G_ * FREQ_) + (size_t)16 * FREQ_ + f;
            stg3[idx] = make_float2(st_re[b3], st_im[b3]);
        }
    }
}

// ================= merged prep B: {WTsw, bvec} (needs ctb/stb) ===============
__global__ __launch_bounds__(256) void k_prepB(const float* __restrict__ Wm_re,
                                               const float* __restrict__ Wm_im,
                                               const float* __restrict__ bm_re,
                                               const float* __restrict__ bm_im,
                                               const float* __restrict__ ctb,
                                               const float* __restrict__ stb,
                                               unsigned short* __restrict__ T,
                                               float* __restrict__ bvec) {
    int bid = blockIdx.x, tid = threadIdx.x;
    if (bid < 672) {
        int t = bid * 256 + tid;
        if (t >= 512 * H_) return;
        int k = t / H_, h = t - k * H_;
        float s1 = 0.f, s2 = 0.f;
        if (k < 3 * FREQ_) {
            #pragma unroll 4
            for (int g = 0; g < FREQ_; ++g) {
                float ct = ctb[g * H_ + h];
                float st = stb[g * H_ + h];
                float wr = Wm_re[(size_t)g * (3 * FREQ_) + k];
                float wi = Wm_im[(size_t)g * (3 * FREQ_) + k];
                s1 += wr * ct + wi * st;
                s2 += wr * st - wi * ct;
            }
        }
        int nt = h >> 4, nr = h & 15;
        {
            int kc = k >> 5, kr = k & 31;
            int lane = ((kr >> 3) << 4) | nr;
            T[((size_t)(kc * 21 + nt)) * 512 + lane * 8 + (k & 7)] = f2bf(s1);
        }
        {
            int kk = k + 512;
            int kc = kk >> 5, kr = kk & 31;
            int lane = ((kr >> 3) << 4) | nr;
            T[((size_t)(kc * 21 + nt)) * 512 + lane * 8 + (kk & 7)] = f2bf(s2);
        }
    } else {
        int h = (bid - 672) * 256 + tid;
        if (h >= H_) return;
        float acc = 0.f;
        for (int g = 0; g < FREQ_; ++g)
            acc += bm_re[g] * ctb[g * H_ + h] + bm_im[g] * stb[g * H_ + h];
        bvec[h] = acc;
    }
}

// ================= K1: fused LayerNorm, single x pass. grid (11, 32), 512 thr =
// Phase 1: stream 32c x 512l slice (coalesced), LDS-reduce -> mu/inv.
// Phase 2: re-read slice (L2-hot), normalize, LDS-transpose, write bf16.
__global__ __launch_bounds__(512) void k_ln3(const float* __restrict__ x,
                                             unsigned short* __restrict__ fullbf,
                                             float* __restrict__ muv,
                                             float* __restrict__ nrm) {
    __shared__ float red_s[16][32], red_q[16][32];
    __shared__ float sMu[32], sInv[32];
    __shared__ float tl[64][33];
    int tid = threadIdx.x;
    int c_l = tid & 31, lg = tid >> 5;       // lg 0..15, each covers 32 l
    int b = blockIdx.y, c0 = blockIdx.x * 32;
    int c = c0 + c_l;
    bool valid = (c < C_);
    const float* xb = x + (size_t)b * L_ * C_;

    float s = 0.f, q = 0.f;
    #pragma unroll 8
    for (int i = 0; i < 32; ++i) {
        int l = lg * 32 + i;
        float v = valid ? xb[(size_t)l * C_ + c] : 0.f;
        s += v; q += v * v;
    }
    red_s[lg][c_l] = s; red_q[lg][c_l] = q;
    __syncthreads();
    if (tid < 32) {
        float S = 0.f, Q = 0.f;
        #pragma unroll
        for (int g = 0; g < 16; ++g) { S += red_s[g][tid]; Q += red_q[g][tid]; }
        float mu = S / (float)L_;
        float var = Q / (float)L_ - mu * mu;
        float n = sqrtf(var + EPS_);
        sMu[tid] = mu; sInv[tid] = 1.0f / n;
        if (c0 + tid < C_) {
            muv[(size_t)b * C_ + c0 + tid] = mu;
            nrm[(size_t)b * C_ + c0 + tid] = n;
        }
    }
    __syncthreads();
    float mu = sMu[c_l], inv = sInv[c_l];

    for (int l0 = 0; l0 < L_; l0 += 64) {
        for (int li = lg; li < 64; li += 16) {
            float v = valid ? xb[(size_t)(l0 + li) * C_ + c] : 0.f;
            tl[li][c_l] = (v - mu) * inv;
        }
        __syncthreads();
        #pragma unroll
        for (int t = 0; t < 2; ++t) {
            int idx = tid + t * 512;
            int cr = idx >> 5, j = idx & 31;
            int cc = c0 + cr;
            if (cc < C_) {
                size_t bc = (size_t)b * C_ + cc;
                unsigned pk = (unsigned)f2bf(tl[2 * j][cr]) |
                              ((unsigned)f2bf(tl[2 * j + 1][cr]) << 16);
                ((unsigned*)fullbf)[(bc * LHB_ + l0) / 2 + j] = pk;
            }
        }
        __syncthreads();
    }
}

// ================= K2: merged {y_hat GEMM | p-softmax} =======================
// bid < 642: y_hat via MFMA (bc-tile 32, N half split). bid >= 642: p2 (16 bc).
__global__ __launch_bounds__(256) void k_hp(const unsigned short* __restrict__ fullbf,
                                            const unsigned short* __restrict__ Wbsw,
                                            const float* __restrict__ bb,
                                            const float* __restrict__ r,
                                            const float* __restrict__ Wc,
                                            const float* __restrict__ bcv,
                                            unsigned short* __restrict__ fullbf_w,
                                            float* __restrict__ p_out) {
    __shared__ float WcS[8 * F_FEAT];
    __shared__ float rsS[16][8];
    __shared__ float bcS[8];
    int bid = blockIdx.x;
    int tid = threadIdx.x, w = tid >> 6, lane = tid & 63;

    if (bid < 642) {
        // ---- y_hat GEMM ----
        int bc0 = (bid >> 1) * 32;
        int half = bid & 1;
        const int NTB0[5] = {0, 3, 6, 9, 11};
        const int NTB1[5] = {11, 14, 17, 19, 21};
        int nt0 = half ? NTB1[w] : NTB0[w];
        int ntn = (half ? NTB1[w + 1] : NTB0[w + 1]) - nt0;
        int r15 = lane & 15, kg = lane >> 4;
        f32x4 acc[2][3];
        #pragma unroll
        for (int mf = 0; mf < 2; ++mf)
            #pragma unroll
            for (int j = 0; j < 3; ++j) acc[mf][j] = (f32x4){0.f, 0.f, 0.f, 0.f};
        for (int kc = 0; kc < 16; ++kc) {
            short8v a[2];
            #pragma unroll
            for (int mf = 0; mf < 2; ++mf)
                a[mf] = *(const short8v*)(fullbf + ((size_t)(bc0 + mf * 16 + r15) * LHB_ + kc * 32 + kg * 8));
            #pragma unroll
            for (int j = 0; j < 3; ++j) {
                if (j >= ntn) continue;
                short8v bfr = *(const short8v*)(Wbsw + ((size_t)(kc * 21 + nt0 + j) * 512 + lane * 8));
                #pragma unroll
                for (int mf = 0; mf < 2; ++mf)
                    acc[mf][j] = __builtin_amdgcn_mfma_f32_16x16x32_bf16(a[mf], bfr, acc[mf][j], 0, 0, 0);
            }
        }
        #pragma unroll
        for (int mf = 0; mf < 2; ++mf)
            #pragma unroll
            for (int j = 0; j < 3; ++j) {
                if (j >= ntn) continue;
                int n_ = (nt0 + j) * 16 + r15;
                #pragma unroll
                for (int reg = 0; reg < 4; ++reg) {
                    int bc = bc0 + mf * 16 + kg * 4 + reg;
                    fullbf_w[(size_t)bc * LHB_ + L_ + n_] = f2bf(acc[mf][j][reg] + bb[n_]);
                }
            }
    } else {
        // ---- p softmax ----
        int bc0 = (bid - 642) * 16;
        for (int i = tid; i < 8 * F_FEAT; i += 256) WcS[i] = Wc[i];
        if (tid < 8) bcS[tid] = bcv[tid];
        if (tid < 16) {
            int bc = bc0 + tid;
            const float* rr = r + (size_t)bc * K_;
            float a[8]; float m = 1.0f;
            #pragma unroll
            for (int k = 0; k < 8; ++k) { a[k] = fabsf(rr[k]); m = fmaxf(m, a[k]); }
            float Z = expf(1.0f - m);
            float e[8];
            #pragma unroll
            for (int k = 0; k < 8; ++k) { e[k] = expf(a[k] - m); Z += e[k]; }
            float inv = 1.0f / Z;
            #pragma unroll
            for (int k = 0; k < 8; ++k) rsS[tid][k] = e[k] * inv;
        }
        __syncthreads();

        for (int i = 0; i < 4; ++i) {
            int bcl = w * 4 + i;
            int bc = bc0 + bcl;
            const unsigned* xrow = (const unsigned*)(fullbf + (size_t)bc * LHB_);
            float acc[8] = {0.f, 0.f, 0.f, 0.f, 0.f, 0.f, 0.f, 0.f};
            #pragma unroll
            for (int t = 0; t < 4; ++t) {
                int j = lane + t * 64;
                unsigned v = xrow[j];
                float x0 = bf2f((unsigned short)(v & 0xffff));
                float x1 = bf2f((unsigned short)(v >> 16));
                #pragma unroll
                for (int s = 0; s < 8; ++s)
                    acc[s] += x0 * WcS[s * F_FEAT + 2 * j] + x1 * WcS[s * F_FEAT + 2 * j + 1];
            }
            if (lane < 8) {
                float xf = rsS[bcl][lane];
                #pragma unroll
                for (int s = 0; s < 8; ++s) acc[s] += xf * WcS[s * F_FEAT + L_ + lane];
            }
            #pragma unroll
            for (int s = 0; s < 8; ++s) {
                #pragma unroll
                for (int off = 32; off > 0; off >>= 1) acc[s] += __shfl_down(acc[s], off);
            }
            if (lane == 0) {
                float m = -1e30f;
                #pragma unroll
                for (int s = 0; s < 8; ++s) { acc[s] += bcS[s]; m = fmaxf(m, acc[s]); }
                float Z = 0.f; float e[8];
                #pragma unroll
                for (int s = 0; s < 8; ++s) { e[s] = expf(acc[s] - m); Z += e[s]; }
                float inv = 1.0f / Z;
                #pragma unroll
                for (int s = 0; s < 8; ++s) p_out[(size_t)bc * 8 + s] = e[s] * inv;
            }
        }
    }
}

// ================= K4: fused gather + DFT MFMA + filter-combine -> z =========
// XCD-aware bijective block swizzle (T1, m204 chunked formula): contiguous bc
// chunks per XCD so same-batch fullbf slabs stay L2-resident for the gather.
__global__ __launch_bounds__(512) void k_dftz2(const unsigned short* __restrict__ fullbf,
                                               const int* __restrict__ leader,
                                               const int* __restrict__ shiftp,
                                               const unsigned short* __restrict__ Tsw,
                                               const float* __restrict__ pbuf,
                                               const float4* __restrict__ stf4,
                                               const float2* __restrict__ stg3,
                                               unsigned short* __restrict__ zbf) {
    __shared__ unsigned short A[64 * 360];
    __shared__ float psL[DZB_][8];
    int tid = threadIdx.x, w = tid >> 6, lane = tid & 63;
    // bijective chunked XCD swizzle: orig -> swz
    int nblk = gridDim.x;
    int q = nblk >> 3, rmd = nblk & 7;
    int xcd = blockIdx.x & 7, sidx = blockIdx.x >> 3;
    int swz = (xcd < rmd) ? (xcd * (q + 1) + sidx)
                          : (rmd * (q + 1) + (xcd - rmd) * q + sidx);
    int bc0 = swz * DZB_;
    unsigned* A32 = (unsigned*)A;
    for (int i = tid; i < 64 * 180; i += 512) A32[i] = 0;
    if (tid < DZB_ * 8) {
        int bcl = tid >> 3, s = tid & 7;
        int bc = bc0 + bcl;
        psL[bcl][s] = (bc < BCN_) ? pbuf[(size_t)bc * 8 + s] : 0.f;
    }
    if (tid >= 64 && tid < 64 + DZB_ * 10) {
        int t = tid - 64;
        int bcl = t / 10, o = t - bcl * 10;
        int bc = bc0 + bcl;
        if (bc < BCN_) {
            unsigned short* zrow = zbf + (size_t)bc * 1024;
            if (o < 5) zrow[507 + o] = 0;
            else       zrow[1019 + (o - 5)] = 0;
        }
    }
    __syncthreads();

    #pragma unroll
    for (int i = 0; i < 8; ++i) {
        int rr = w * 8 + i;
        if (rr >= 63) break;
        int bcl = rr / 9, k = rr - bcl * 9;
        int bc = bc0 + bcl;
        if (bc < BCN_) {
            int b = bc / C_;
            const unsigned short* src;
            if (k < 8) {
                int lead = leader[(size_t)bc * K_ + k];
                int sh = shiftp[(size_t)bc * K_ + k];
                src = fullbf + ((size_t)b * C_ + lead) * LHB_ + (L_ - sh);
            } else {
                src = fullbf + (size_t)bc * LHB_ + L_;
            }
            unsigned short* dst = A + rr * 360;
            #pragma unroll
            for (int t = 0; t < 6; ++t) {
                int j = lane + t * 64;
                if (j < H_) dst[j] = src[j];
            }
        }
    }
    __syncthreads();

    const int NTB[9] = {0, 3, 6, 9, 11, 14, 17, 20, 22};
    int nt0 = NTB[w], ntn = NTB[w + 1] - nt0;
    int r15 = lane & 15, kg = lane >> 4;
    f32x4 acc[4][3];
    #pragma unroll
    for (int mf = 0; mf < 4; ++mf)
        #pragma unroll
        for (int j = 0; j < 3; ++j) acc[mf][j] = (f32x4){0.f, 0.f, 0.f, 0.f};
    for (int kc = 0; kc < 11; ++kc) {
        short8v a[4];
        #pragma unroll
        for (int mf = 0; mf < 4; ++mf)
            a[mf] = *(const short8v*)(A + (size_t)(mf * 16 + r15) * 360 + kc * 32 + kg * 8);
        #pragma unroll
        for (int j = 0; j < 3; ++j) {
            if (j >= ntn) continue;
            short8v bfr = *(const short8v*)(Tsw + ((size_t)(kc * 22 + nt0 + j) * 512 + lane * 8));
            #pragma unroll
            for (int mf = 0; mf < 4; ++mf)
                acc[mf][j] = __builtin_amdgcn_mfma_f32_16x16x32_bf16(a[mf], bfr, acc[mf][j], 0, 0, 0);
        }
    }
    __syncthreads();

    #pragma unroll
    for (int mf = 0; mf < 4; ++mf)
        #pragma unroll
        for (int j = 0; j < 3; ++j) {
            if (j >= ntn) continue;
            int col = (nt0 + j) * 16 + r15;
            #pragma unroll
            for (int reg = 0; reg < 4; ++reg) {
                int row = mf * 16 + kg * 4 + reg;
                A[row * 360 + col] = f2bf(acc[mf][j][reg]);
            }
        }
    __syncthreads();

    if (tid < 507) {
        int g = tid / 169;
        int f = tid - g * 169;
        int bclo = (g == 0) ? 0 : (g == 1) ? 3 : 5;
        int nb   = (g == 0) ? 3 : 2;
        float z1r[3], z1i[3], z2r[3], z2i[3], Yr[3], Yi[3];
        #pragma unroll
        for (int bl = 0; bl < 3; ++bl) {
            z1r[bl] = z1i[bl] = z2r[bl] = z2i[bl] = 0.f;
            unsigned v = (bl < nb) ? A32[((bclo + bl) * 9 + 8) * 180 + f] : 0u;
            Yr[bl] = bf2f((unsigned short)(v & 0xffff));
            Yi[bl] = bf2f((unsigned short)(v >> 16));
        }
        for (int k = 0; k < 8; ++k) {
            float4 stv[8];
            #pragma unroll
            for (int s = 0; s < 8; ++s) stv[s] = stf4[(size_t)(k * 8 + s) * FREQ_ + f];
            #pragma unroll
            for (int bl = 0; bl < 3; ++bl) {
                if (bl >= nb) continue;
                int bcl = bclo + bl;
                float f1r = 0.f, f1i = 0.f, f2r = 0.f, f2i = 0.f;
                #pragma unroll
                for (int s = 0; s < 8; ++s) {
                    float p = psL[bcl][s];
                    f1r += p * stv[s].x; f1i += p * stv[s].y;
                    f2r += p * stv[s].z; f2i += p * stv[s].w;
                }
                unsigned v = A32[(bcl * 9 + k) * 180 + f];
                float Xr = bf2f((unsigned short)(v & 0xffff));
                float Xi = bf2f((unsigned short)(v >> 16));
                float ar = Xr * f1r - Xi * f1i;
                float ai = Xr * f1i + Xi * f1r;
                z1r[bl] += ar; z1i[bl] += ai;
                float dr = ar - Yr[bl], di = ai - Yi[bl];
                z2r[bl] += dr * f2r - di * f2i;
                z2i[bl] += dr * f2i + di * f2r;
            }
        }
        #pragma unroll
        for (int bl = 0; bl < 3; ++bl) {
            if (bl >= nb) continue;
            int bcl = bclo + bl;
            int bc = bc0 + bcl;
            if (bc >= BCN_) continue;
            float f3r = 0.f, f3i = 0.f;
            #pragma unroll
            for (int s = 0; s < 8; ++s) {
                float2 v3 = stg3[(size_t)s * FREQ_ + f];
                float p = psL[bcl][s];
                f3r += p * v3.x; f3i += p * v3.y;
            }
            unsigned short* zrow = zbf + (size_t)bc * 1024;
            zrow[f]       = f2bf(z1r[bl]);  zrow[512 + f]       = f2bf(z1i[bl]);
            zrow[169 + f] = f2bf(z2r[bl]);  zrow[512 + 169 + f] = f2bf(z2i[bl]);
            zrow[338 + f] = f2bf(Yr[bl] * f3r - Yi[bl] * f3i);
            zrow[512 + 338 + f] = f2bf(Yr[bl] * f3i + Yi[bl] * f3r);
        }
    }
}

// ================= K6: fused (mix+irfft) GEMM + transposed store =============
// y_add = z @ WT + bvec; y_hat read as bf16 from fullbf; denorm; store out.
__global__ __launch_bounds__(256) void k_mixf2(const unsigned short* __restrict__ zbf,
                                               const unsigned short* __restrict__ WTsw,
                                               const float* __restrict__ bvec,
                                               const unsigned short* __restrict__ fullbf,
                                               const float* __restrict__ muv,
                                               const float* __restrict__ nrm,
                                               float* __restrict__ out) {
    __shared__ float ytile[32][177];
    int bc0 = blockIdx.x * 32;
    int half = blockIdx.y;
    int tid = threadIdx.x, w = tid >> 6, lane = tid & 63;
    const int NTB0[5] = {0, 3, 6, 9, 11};
    const int NTB1[5] = {11, 14, 17, 19, 21};
    int nt0 = half ? NTB1[w] : NTB0[w];
    int ntn = (half ? NTB1[w + 1] : NTB0[w + 1]) - nt0;
    int h0 = half ? 176 : 0;
    int hn = half ? 160 : 176;
    int r15 = lane & 15, kg = lane >> 4;
    f32x4 acc[2][3];
    #pragma unroll
    for (int mf = 0; mf < 2; ++mf)
        #pragma unroll
        for (int j = 0; j < 3; ++j) acc[mf][j] = (f32x4){0.f, 0.f, 0.f, 0.f};
    for (int kc = 0; kc < 32; ++kc) {
        short8v a[2];
        #pragma unroll
        for (int mf = 0; mf < 2; ++mf)
            a[mf] = *(const short8v*)(zbf + ((size_t)(bc0 + mf * 16 + r15) * 1024 + kc * 32 + kg * 8));
        #pragma unroll
        for (int j = 0; j < 3; ++j) {
            if (j >= ntn) continue;
            short8v bfr = *(const short8v*)(WTsw + ((size_t)(kc * 21 + nt0 + j) * 512 + lane * 8));
            #pragma unroll
            for (int mf = 0; mf < 2; ++mf)
                acc[mf][j] = __builtin_amdgcn_mfma_f32_16x16x32_bf16(a[mf], bfr, acc[mf][j], 0, 0, 0);
        }
    }
    #pragma unroll
    for (int mf = 0; mf < 2; ++mf)
        #pragma unroll
        for (int j = 0; j < 3; ++j) {
            if (j >= ntn) continue;
            int h = (nt0 + j) * 16 + r15;
            float bv = bvec[h];
            #pragma unroll
            for (int reg = 0; reg < 4; ++reg) {
                int bcl = mf * 16 + kg * 4 + reg;
                int bc = bc0 + bcl;
                float yh = bf2f(fullbf[(size_t)bc * LHB_ + L_ + h]);
                float y = (yh + acc[mf][j][reg] + bv) * nrm[bc] + muv[bc];
                ytile[bcl][h - h0] = y;
            }
        }
    __syncthreads();
    for (int idx = tid; idx < 32 * hn; idx += 256) {
        int bcl = idx & 31, hrel = idx >> 5;
        int bc = bc0 + bcl;
        int b = bc / C_, c = bc - b * C_;
        out[((size_t)b * H_ + h0 + hrel) * C_ + c] = ytile[bcl][hrel];
    }
}

extern "C" void kernel_launch(void* const* d_in, const int* in_sizes, int n_in,
                              void* d_out, int out_size, void* d_ws, size_t ws_size,
                              hipStream_t stream) {
    const float* x     = (const float*)d_in[0];
    const float* r     = (const float*)d_in[1];
    const float* Wb    = (const float*)d_in[2];
    const float* bb    = (const float*)d_in[3];
    const float* Wc    = (const float*)d_in[4];
    const float* bcv   = (const float*)d_in[5];
    const float* st_re = (const float*)d_in[6];
    const float* st_im = (const float*)d_in[7];
    const float* Wm_re = (const float*)d_in[8];
    const float* Wm_im = (const float*)d_in[9];
    const float* bm_re = (const float*)d_in[10];
    const float* bm_im = (const float*)d_in[11];
    const int* leader  = (const int*)d_in[12];
    const int* shiftp  = (const int*)d_in[13];
    float* out = (float*)d_out;

    char* w = (char*)d_ws;
    auto carve = [&](size_t bytes) {
        char* p = w;
        w += (bytes + 255) & ~(size_t)255;
        return (void*)p;
    };
    unsigned short* Tdft = (unsigned short*)carve((size_t)11 * 22 * 512 * 2);
    unsigned short* WTsw = (unsigned short*)carve((size_t)32 * 21 * 512 * 2);
    unsigned short* Wbsw = (unsigned short*)carve((size_t)16 * 21 * 512 * 2);
    float*          ctb  = (float*)carve((size_t)FREQ_ * H_ * 4);
    float*          stb  = (float*)carve((size_t)FREQ_ * H_ * 4);
    float*          bvec = (float*)carve((size_t)H_ * 4);
    float4*         stf4 = (float4*)carve((size_t)64 * FREQ_ * 16);
    float2*         stg3 = (float2*)carve((size_t)8 * FREQ_ * 8);
    unsigned short* fullbf = (unsigned short*)carve((size_t)BCN_ * LHB_ * 2);
    float*          muv  = (float*)carve((size_t)BCN_ * 4);
    float*          nrm  = (float*)carve((size_t)BCN_ * 4);
    float*          pbuf = (float*)carve((size_t)BCN_ * 8 * 4);
    unsigned short* zbf  = (unsigned short*)carve((size_t)BCN_ * 1024 * 2);

    hipLaunchKernelGGL(k_prepA, dim3(410), dim3(256), 0, stream,
                       Wb, st_re, st_im, Tdft, ctb, stb, Wbsw, stf4, stg3);
    hipLaunchKernelGGL(k_prepB, dim3(674), dim3(256), 0, stream,
                       Wm_re, Wm_im, bm_re, bm_im, ctb, stb, WTsw, bvec);
    hipLaunchKernelGGL(k_ln3, dim3(11, 32), dim3(512), 0, stream, x, fullbf, muv, nrm);
    hipLaunchKernelGGL(k_hp, dim3(642 + 642), dim3(256), 0, stream,
                       fullbf, Wbsw, bb, r, Wc, bcv, fullbf, pbuf);
    hipLaunchKernelGGL(k_dftz2, dim3((BCN_ + DZB_ - 1) / DZB_), dim3(512), 0, stream,
                       fullbf, leader, shiftp, Tdft, pbuf, stf4, stg3, zbf);
    hipLaunchKernelGGL(k_mixf2, dim3(BCN_ / 32, 2), dim3(256), 0, stream,
                       zbf, WTsw, bvec, fullbf, muv, nrm, out);
}